// Round 1
// 908.361 us; speedup vs baseline: 1.0124x; 1.0124x over previous
//
#include <hip/hip_runtime.h>
#include <stdint.h>
#include <math.h>

// Problem constants (B=2, T=2048, C=2048, NH=16, NG=4, HS=128)
#define Tn   2048
#define Cn   2048
#define BTn  4096          // B*T
#define NQKV 3072          // (16+2*4)*128
#define HID  8192

typedef unsigned short u16;
typedef float f32x4 __attribute__((ext_vector_type(4)));
typedef short s16x8 __attribute__((ext_vector_type(8)));   // 8 bf16 in 4 VGPRs

__device__ __forceinline__ float b2f(u16 u) { return __uint_as_float(((unsigned)u) << 16); }
__device__ __forceinline__ u16 f2b(float f) {
  unsigned i = __float_as_uint(f);
  return (u16)((i + 0x7fffu + ((i >> 16) & 1u)) >> 16);   // RNE
}

// async 16B global->LDS (lds dest is wave-uniform base; HW scatters lane*16)
__device__ __forceinline__ void g2l16(const void* g, void* l) {
  __builtin_amdgcn_global_load_lds((const __attribute__((address_space(1))) unsigned int*)g,
                                   (__attribute__((address_space(3))) unsigned int*)l,
                                   16, 0, 0);
}

// ------- tiled transpose + fp32->bf16 cast: out[c][r] = bf16(in[r][c]) -------
__global__ __launch_bounds__(256) void transpose_f2b(const float* __restrict__ in,
                                                     u16* __restrict__ out, int R, int C) {
  __shared__ float tile[32][33];
  int bx = blockIdx.x * 32, by = blockIdx.y * 32;
  int tx = threadIdx.x, ty = threadIdx.y;  // (32,8)
  #pragma unroll
  for (int j = 0; j < 32; j += 8)
    tile[ty + j][tx] = in[(size_t)(by + ty + j) * C + bx + tx];
  __syncthreads();
  #pragma unroll
  for (int j = 0; j < 32; j += 8)
    out[(size_t)(bx + ty + j) * R + by + tx] = f2b(tile[tx][ty + j]);
}

// ------- tiled u16 transpose with batch dim: out[z][c][r] = in[z][r][c] -------
__global__ __launch_bounds__(256) void transpose_u16(const u16* __restrict__ in,
                                                     u16* __restrict__ out, int R, int C) {
  __shared__ u16 tile[32][33];
  const size_t zb = (size_t)blockIdx.z * R * C;
  int bx = blockIdx.x * 32, by = blockIdx.y * 32;
  int tx = threadIdx.x, ty = threadIdx.y;  // (32,8)
  #pragma unroll
  for (int j = 0; j < 32; j += 8)
    tile[ty + j][tx] = in[zb + (size_t)(by + ty + j) * C + bx + tx];
  __syncthreads();
  #pragma unroll
  for (int j = 0; j < 32; j += 8)
    out[zb + (size_t)(bx + ty + j) * R + by + tx] = tile[tx][ty + j];
}

// ---------------- layernorm: fp32 in, bf16 out ----------------
__global__ __launch_bounds__(256)
void layernorm_k(const float* __restrict__ x, const float* __restrict__ w,
                 const float* __restrict__ bb, u16* __restrict__ out) {
  __shared__ float red[256];
  __shared__ float sm, sv;
  const int tid = threadIdx.x;
  const long row = blockIdx.x;
  const float* xr = x + row * (long)Cn;
  float v[8];
  float s = 0.f;
  #pragma unroll
  for (int i = 0; i < 8; ++i) { v[i] = xr[i * 256 + tid]; s += v[i]; }
  red[tid] = s; __syncthreads();
  for (int st = 128; st > 0; st >>= 1) { if (tid < st) red[tid] += red[tid + st]; __syncthreads(); }
  if (tid == 0) sm = red[0] * (1.f / Cn);
  __syncthreads();
  const float mean = sm;
  float s2 = 0.f;
  #pragma unroll
  for (int i = 0; i < 8; ++i) { float d = v[i] - mean; s2 += d * d; }
  red[tid] = s2; __syncthreads();
  for (int st = 128; st > 0; st >>= 1) { if (tid < st) red[tid] += red[tid + st]; __syncthreads(); }
  if (tid == 0) sv = rsqrtf(red[0] * (1.f / Cn) + 1e-5f);
  __syncthreads();
  const float rstd = sv;
  #pragma unroll
  for (int i = 0; i < 8; ++i) {
    int c = i * 256 + tid;
    out[row * (long)Cn + c] = f2b((v[i] - mean) * rstd * w[c] + bb[c]);
  }
}

// ---- RoPE + split qkv(bf16) -> q[b,h,t,d], k[b,g,t,d], v[b,g,t,d] (bf16) ----
__global__ __launch_bounds__(256)
void rope_split(const u16* __restrict__ qkv, const float* __restrict__ cs,
                const float* __restrict__ sn, u16* __restrict__ q,
                u16* __restrict__ k, u16* __restrict__ v) {
  const long idx = (long)blockIdx.x * 256 + threadIdx.x;
  const int row = (int)(idx / NQKV);       // b*T + t
  const int col = (int)(idx % NQKV);
  const int b = row >> 11, t = row & 2047;
  const int g = col / 768, rr = col % 768, s = rr >> 7, d = rr & 127;
  const u16 raw = qkv[idx];
  if (s == 5) { v[((long)(b * 4 + g) * Tn + t) * 128 + d] = raw; return; }
  const float xv = b2f(raw);
  const float x2 = b2f(qkv[idx - d + (d ^ 64)]);
  const float c = cs[t * 128 + d];
  const float si = sn[t * 128 + d];
  const float rot = (d < 64) ? -x2 : x2;
  const float o = xv * c + rot * si;
  if (s == 4) k[((long)(b * 4 + g) * Tn + t) * 128 + d] = f2b(o);
  else        q[((long)(b * 16 + g * 4 + s) * Tn + t) * 128 + d] = f2b(o);
}

// ------------- MFMA flash attention (causal GQA), bf16 I/O -------------
// Grid (T/64, B*NH). 4 waves; wave w owns Q rows bx*64+w*16 .. +15.
__global__ __launch_bounds__(256, 2)
void attn_flash(const u16* __restrict__ q, const u16* __restrict__ k,
                const u16* __restrict__ vt, u16* __restrict__ y) {
  __shared__ __align__(16) u16 Ks[4 * 64 * 32];     // 16 KB
  __shared__ __align__(16) u16 Vs[2 * 128 * 32];    // 16 KB
  __shared__ __align__(16) u16 Ps[4][2 * 16 * 32];  // 8 KB (per-wave)
  const int tid = threadIdx.x, wave = tid >> 6, lane = tid & 63;
  const int fr = lane & 15, quad = lane >> 4;
  const int lr4 = lane >> 2, lc8 = (lane & 3) << 3;
  const int bx = blockIdx.x, bh = blockIdx.y;
  const int b = bh >> 4, h = bh & 15, g = h >> 2;
  const int bg = b * 4 + g;
  const u16* kg = k + (size_t)bg * Tn * 128;
  const u16* vg = vt + (size_t)bg * 128 * Tn;
  const int q0 = bx * 64 + wave * 16;

  // Q fragments in registers: A[m=fr][k=kc*32+quad*8+j]
  s16x8 qf[4];
  {
    const u16* qrow = q + ((size_t)bh * Tn + q0 + fr) * 128;
    #pragma unroll
    for (int kc = 0; kc < 4; ++kc)
      qf[kc] = *(const s16x8*)(qrow + kc * 32 + quad * 8);
  }
  f32x4 o_acc[8] = {};                 // O[16][128], C-layout per 16-col tile
  float m_r[4], l_r[4];
  #pragma unroll
  for (int r = 0; r < 4; ++r) { m_r[r] = -1e30f; l_r[r] = 0.f; }
  const float scale = 0.08838834764831845f;  // 1/sqrt(128)

  for (int step = 0; step <= bx; ++step) {
    const int j0 = step * 64;
    __syncthreads();                   // prior iter's LDS reads done
    #pragma unroll
    for (int kc = 0; kc < 4; ++kc)
      g2l16(kg + (size_t)(j0 + wave * 16 + lr4) * 128 + kc * 32 + lc8,
            Ks + kc * 2048 + wave * 16 * 32);
    #pragma unroll
    for (int kc = 0; kc < 2; ++kc)
      #pragma unroll
      for (int hh = 0; hh < 2; ++hh)
        g2l16(vg + (size_t)(wave * 32 + hh * 16 + lr4) * Tn + j0 + kc * 32 + lc8,
              Vs + kc * 4096 + (wave * 32 + hh * 16) * 32);
    __syncthreads();                   // vmcnt(0) drain by compiler

    // S = Q * K^T  (16x64 per wave)
    f32x4 s[4] = {};
    #pragma unroll
    for (int kc = 0; kc < 4; ++kc)
      #pragma unroll
      for (int nt = 0; nt < 4; ++nt) {
        s16x8 bf = *(const s16x8*)(Ks + kc * 2048 + (nt * 16 + fr) * 32 + quad * 8);
        s[nt] = __builtin_amdgcn_mfma_f32_16x16x32_bf16(qf[kc], bf, s[nt], 0, 0, 0);
      }

    // online softmax; rows = q0 + quad*4 + r, cols = j0 + nt*16 + fr
    const bool diag = (step == bx);
    #pragma unroll
    for (int r = 0; r < 4; ++r) {
      float vmax = -1e30f;
      #pragma unroll
      for (int nt = 0; nt < 4; ++nt) {
        float sv = s[nt][r] * scale;
        if (diag && (j0 + nt * 16 + fr) > (q0 + quad * 4 + r)) sv = -1e30f;
        s[nt][r] = sv;
        vmax = fmaxf(vmax, sv);
      }
      #pragma unroll
      for (int mk = 1; mk < 16; mk <<= 1) vmax = fmaxf(vmax, __shfl_xor(vmax, mk, 64));
      const float mnew = fmaxf(m_r[r], vmax);
      const float alpha = __expf(m_r[r] - mnew);
      float rsum = 0.f;
      #pragma unroll
      for (int nt = 0; nt < 4; ++nt) {
        float pv = __expf(s[nt][r] - mnew);
        s[nt][r] = pv; rsum += pv;
      }
      #pragma unroll
      for (int mk = 1; mk < 16; mk <<= 1) rsum += __shfl_xor(rsum, mk, 64);
      l_r[r] = l_r[r] * alpha + rsum;
      m_r[r] = mnew;
      #pragma unroll
      for (int nt = 0; nt < 8; ++nt) o_acc[nt][r] *= alpha;
    }

    // P (C-layout) -> LDS panels (bf16), then A-frag reads
    u16* pw = Ps[wave];
    #pragma unroll
    for (int nt = 0; nt < 4; ++nt) {
      const int col = nt * 16 + fr, pan = col >> 5, cc = col & 31;
      #pragma unroll
      for (int r = 0; r < 4; ++r)
        pw[pan * 512 + (quad * 4 + r) * 32 + cc] = f2b(s[nt][r]);
    }
    // O += P * V  (k = t-dim, 2 panels of 32)
    #pragma unroll
    for (int kc = 0; kc < 2; ++kc) {
      s16x8 af = *(const s16x8*)(pw + kc * 512 + fr * 32 + quad * 8);
      #pragma unroll
      for (int nt = 0; nt < 8; ++nt) {
        s16x8 bf = *(const s16x8*)(Vs + kc * 4096 + (nt * 16 + fr) * 32 + quad * 8);
        o_acc[nt] = __builtin_amdgcn_mfma_f32_16x16x32_bf16(af, bf, o_acc[nt], 0, 0, 0);
      }
    }
  }

  // epilogue: y[b, t, h*128 + d] = O / l
  #pragma unroll
  for (int r = 0; r < 4; ++r) {
    const float inv = 1.f / l_r[r];
    const size_t row = (size_t)(b * Tn + q0 + quad * 4 + r) * Cn + h * 128;
    #pragma unroll
    for (int nt = 0; nt < 8; ++nt)
      y[row + nt * 16 + fr] = f2b(o_acc[nt][r] * inv);
  }
}

// ================= 256x256 8-phase MFMA GEMM (T2+T3+T4+T5) =================
// BM=BN=256, BK=64, 512 threads = 8 waves (2M x 4N), per-wave C = 128x64.
// LDS 128 KB: A[2buf][2half][128x64 bf16], B same at +64KB. st_16x32 XOR
// swizzle (bit9->bit5) realized as linear g2l16 dest + inverse-swizzled
// global source + swizzled ds_read (both-sides-or-neither rule).
// Phase: {ds_read frags | stage 1 half-tile} -> barrier -> lgkmcnt(0) ->
// setprio(1) 16xMFMA setprio(0) -> [vmcnt(4) @P4/P8] -> barrier.
// Requires M%256==0, N%256==0, K%128==0, grid%8==0 (all shapes here ok).
// EPI 0: ob=bf16(acc); EPI 1: of=acc+res (fp32); EPI 2: ob=bf16(gelu(acc))
#define BAR  __builtin_amdgcn_s_barrier()
#define LG0  asm volatile("s_waitcnt lgkmcnt(0)" ::: "memory")
#define RD_A(BUF, MI4)                                                                  \
  { _Pragma("unroll") for (int m_ = 0; m_ < 4; ++m_) {                                  \
      _Pragma("unroll") for (int k_ = 0; k_ < 2; ++k_)                                  \
        ar[m_][k_] = *(const s16x8*)(Sb + (BUF) * 32768 + aBase +                       \
                                     (((MI4) + m_) << 11) + (k_ << 10) + fragoff); } }
#define RD_B(BUF, NI2, DST)                                                             \
  { _Pragma("unroll") for (int n_ = 0; n_ < 2; ++n_) {                                  \
      _Pragma("unroll") for (int k_ = 0; k_ < 2; ++k_)                                  \
        DST[n_][k_] = *(const s16x8*)(Sb + (BUF) * 32768 + bBase +                      \
                                      (((NI2) + n_) << 11) + (k_ << 10) + fragoff); } }
#define MM(MB, NB, BR)                                                                  \
  { __builtin_amdgcn_s_setprio(1);                                                     \
    _Pragma("unroll") for (int m_ = 0; m_ < 4; ++m_) {                                  \
      _Pragma("unroll") for (int n_ = 0; n_ < 2; ++n_) {                                \
        _Pragma("unroll") for (int k_ = 0; k_ < 2; ++k_)                                \
          acc[(MB) + m_][(NB) + n_] = __builtin_amdgcn_mfma_f32_16x16x32_bf16(          \
              ar[m_][k_], BR[n_][k_], acc[(MB) + m_][(NB) + n_], 0, 0, 0); } }          \
    __builtin_amdgcn_s_setprio(0); }

template <int EPI>
__global__ __launch_bounds__(512, 2)
void gemm256(const u16* __restrict__ A, const u16* __restrict__ Bt,
             const float* __restrict__ res, u16* __restrict__ ob,
             float* __restrict__ of, int M, int N, int K, int num_n) {
  __shared__ __align__(16) u16 S[65536];   // 128 KB
  char* Sb = (char*)S;
  (void)M;

  // XCD-aware 2x2-patch swizzle: xcd = pid&7 owns whole 2x2 tile patches ->
  // A/B panels reused 2x from its L2 (patch WS @K=2048: 4 MB ~= one XCD L2).
  const int pid = blockIdx.x;
  const int xcd = pid & 7, idx = pid >> 3;
  const int jj = idx & 3;
  const int gp = (idx >> 2) * 8 + xcd;
  const int npc = num_n >> 1;
  const int pr = gp / npc, pc = gp - pr * npc;
  const long m0 = (long)(pr * 2 + (jj >> 1)) * 256;
  const long n0 = (long)(pc * 2 + (jj & 1)) * 256;

  const int tid = (int)threadIdx.x;
  const int wave = tid >> 6, lane = tid & 63;
  const int wr = wave >> 2, wc = wave & 3;          // wave grid 2M x 4N
  const int fr = lane & 15, quad = lane >> 4;
  // fragment ds_read byte offset within 16KB region, st_16x32-swizzled
  const int fragoff = (fr * 64 + quad * 16) ^ (((fr >> 3) & 1) << 5);
  const int aBase = wr * 16384;                          // A half = wr
  const int bBase = 65536 + (wc >> 1) * 16384 + ((wc & 1) << 13);  // B half/quarter

  // staging: linear LDS dest d -> logical l = d ^ swz -> (row, kbyte) source
  int srow[2], skcb[2];
  #pragma unroll
  for (int rr = 0; rr < 2; ++rr) {
    const int d = rr * 8192 + wave * 1024 + lane * 16;
    const int l = d ^ (((d >> 9) & 1) << 5);
    srow[rr] = ((l >> 11) << 4) | ((l >> 6) & 15);
    skcb[rr] = (((l >> 10) & 1) << 6) | (l & 63);
  }
  auto stage = [&](const u16* __restrict__ src, long grow0, int kt, int regionByte) {
    #pragma unroll
    for (int rr = 0; rr < 2; ++rr)
      g2l16((const char*)src + (grow0 + srow[rr]) * (long)K * 2 + (long)kt * 128 + skcb[rr],
            Sb + regionByte + rr * 8192 + wave * 1024);
  };

  const int nk = K >> 6;     // 64-wide K-tiles (even, >=4 for all shapes here)
  const int nk2 = nk >> 1;

  // prologue: tile0 -> buf0 (A h0,h1 + B h0,h1), tile1 B -> buf1
  stage(A,  m0,       0, 0);
  stage(A,  m0 + 128, 0, 16384);
  stage(Bt, n0,       0, 65536);
  stage(Bt, n0 + 128, 0, 81920);
  stage(Bt, n0,       1, 98304);
  stage(Bt, n0 + 128, 1, 114688);
  asm volatile("s_waitcnt vmcnt(4)" ::: "memory");   // tile0 landed
  BAR;

  s16x8 ar[4][2], br0[2][2], br1[2][2];
  f32x4 acc[8][4] = {};

  for (int i = 0; i < nk2; ++i) {
    const int t1 = 2 * i + 1, s0 = 2 * i + 2, s1 = 2 * i + 3;
    const bool v0 = (s0 < nk), v1 = (s1 < nk);
    // ---------- K-tile 2i from buf0: phases P1-P4 ----------
    // P1: A mi0-3 + B ni0-1 (12 reads); stage buf1.A h0 <- tile t1
    RD_A(0, 0); RD_B(0, 0, br0);
    stage(A, m0, t1, 32768);
    asm volatile("s_waitcnt lgkmcnt(8)" ::: "memory");
    BAR; LG0; MM(0, 0, br0); BAR;
    // P2: B ni2-3; stage buf1.A h1
    RD_B(0, 2, br1);
    stage(A, m0 + 128, t1, 49152);
    BAR; LG0; MM(0, 2, br1); BAR;
    // P3: A mi4-7; stage buf0.B h0 <- tile s0 (buf0.B reads done end-P2)
    RD_A(0, 4);
    if (v0) stage(Bt, n0, s0, 65536);
    BAR; LG0; MM(4, 2, br1); BAR;
    // P4: no reads; stage buf0.B h1; counted vmcnt -> buf1 (t1) fully landed
    if (v0) stage(Bt, n0 + 128, s0, 81920);
    BAR; LG0; MM(4, 0, br0);
    if (v0) { asm volatile("s_waitcnt vmcnt(4)" ::: "memory"); }
    else    { asm volatile("s_waitcnt vmcnt(0)" ::: "memory"); }
    BAR;
    // ---------- K-tile 2i+1 from buf1: phases P5-P8 ----------
    // P5: stage buf0.A h0 <- tile s0 (buf0.A reads done end-P3)
    RD_A(1, 0); RD_B(1, 0, br0);
    if (v0) stage(A, m0, s0, 0);
    asm volatile("s_waitcnt lgkmcnt(8)" ::: "memory");
    BAR; LG0; MM(0, 0, br0); BAR;
    // P6: stage buf0.A h1
    RD_B(1, 2, br1);
    if (v0) stage(A, m0 + 128, s0, 16384);
    BAR; LG0; MM(0, 2, br1); BAR;
    // P7: stage buf1.B h0 <- tile s1 (buf1.B reads done end-P6)
    RD_A(1, 4);
    if (v1) stage(Bt, n0, s1, 98304);
    BAR; LG0; MM(4, 2, br1); BAR;
    // P8: stage buf1.B h1; counted vmcnt -> buf0 (s0) fully landed
    if (v1) stage(Bt, n0 + 128, s1, 114688);
    BAR; LG0; MM(4, 0, br0);
    asm volatile("s_waitcnt vmcnt(4)" ::: "memory");
    BAR;
  }

  // epilogue: C[row][col], row = m0+wr*128+mi*16+quad*4+r, col = n0+wc*64+ni*16+fr
  #pragma unroll
  for (int mi = 0; mi < 8; ++mi)
    #pragma unroll
    for (int ni = 0; ni < 4; ++ni)
      #pragma unroll
      for (int r = 0; r < 4; ++r) {
        const long row = m0 + wr * 128 + mi * 16 + quad * 4 + r;
        const long col = n0 + wc * 64 + ni * 16 + fr;
        const long idx2 = row * N + col;
        const float vv = acc[mi][ni][r];
        if (EPI == 0) ob[idx2] = f2b(vv);
        else if (EPI == 1) of[idx2] = vv + res[idx2];
        else ob[idx2] = f2b(0.5f * vv * (1.0f + erff(vv * 0.70710678118654752f)));
      }
}

extern "C" void kernel_launch(void* const* d_in, const int* in_sizes, int n_in,
                              void* d_out, int out_size, void* d_ws, size_t ws_size,
                              hipStream_t stream) {
  (void)in_sizes; (void)n_in; (void)out_size; (void)ws_size;
  const float* x      = (const float*)d_in[0];
  const float* cosb   = (const float*)d_in[1];
  const float* sinb   = (const float*)d_in[2];
  const float* ln1w   = (const float*)d_in[3];
  const float* ln1b   = (const float*)d_in[4];
  const float* ln2w   = (const float*)d_in[5];
  const float* ln2b   = (const float*)d_in[6];
  const float* w_attn = (const float*)d_in[7];
  const float* w_proj = (const float*)d_in[8];
  const float* w_fc   = (const float*)d_in[9];
  const float* w_mp   = (const float*)d_in[10];
  float* out = (float*)d_out;

  char* p = (char*)d_ws;
  auto alloc = [&](size_t bytes) { char* r = p; p += (bytes + 255) & ~(size_t)255; return (void*)r; };
  u16*  wT_attn = (u16*)alloc((size_t)NQKV * Cn * 2);   // bf16 [3072][2048]
  u16*  wT_proj = (u16*)alloc((size_t)Cn * Cn * 2);     // bf16 [2048][2048]
  u16*  wT_fc   = (u16*)alloc((size_t)HID * Cn * 2);    // bf16 [8192][2048]
  u16*  wT_mp   = (u16*)alloc((size_t)Cn * HID * 2);    // bf16 [2048][8192]
  u16*  n12     = (u16*)alloc((size_t)BTn * Cn * 2);    // n1 / vt(attn phase) / n2
  u16*  qkv     = (u16*)alloc((size_t)BTn * NQKV * 2);  // qkv, then y (bf16)
  u16*  qb      = (u16*)alloc((size_t)2 * 16 * Tn * 128 * 2);
  u16*  kb      = (u16*)alloc((size_t)2 * 4 * Tn * 128 * 2);
  u16*  vb      = (u16*)alloc((size_t)2 * 4 * Tn * 128 * 2);
  float* x1     = (float*)alloc((size_t)BTn * Cn * 4);  // residual stream (fp32)
  u16*  hbuf    = (u16*)alloc((size_t)BTn * HID * 2);   // gelu(fc) output (bf16)
  u16*  vt      = n12;                                  // [b,g,d,t] transposed V

  dim3 tb(32, 8);
  transpose_f2b<<<dim3(NQKV / 32, Cn / 32), tb, 0, stream>>>(w_attn, wT_attn, Cn, NQKV);
  transpose_f2b<<<dim3(Cn / 32, Cn / 32), tb, 0, stream>>>(w_proj, wT_proj, Cn, Cn);
  transpose_f2b<<<dim3(HID / 32, Cn / 32), tb, 0, stream>>>(w_fc, wT_fc, Cn, HID);
  transpose_f2b<<<dim3(Cn / 32, HID / 32), tb, 0, stream>>>(w_mp, wT_mp, HID, Cn);

  layernorm_k<<<BTn, 256, 0, stream>>>(x, ln1w, ln1b, n12);
  gemm256<0><<<(BTn / 256) * (NQKV / 256), 512, 0, stream>>>(n12, wT_attn, nullptr, qkv, nullptr, BTn, NQKV, Cn, NQKV / 256);
  rope_split<<<(int)(((long)BTn * NQKV) / 256), 256, 0, stream>>>(qkv, cosb, sinb, qb, kb, vb);
  transpose_u16<<<dim3(128 / 32, Tn / 32, 8), tb, 0, stream>>>(vb, vt, Tn, 128);
  attn_flash<<<dim3(Tn / 64, 32), 256, 0, stream>>>(qb, kb, vt, qkv /* y reuse */);
  gemm256<1><<<(BTn / 256) * (Cn / 256), 512, 0, stream>>>(qkv, wT_proj, x, nullptr, x1, BTn, Cn, Cn, Cn / 256);
  layernorm_k<<<BTn, 256, 0, stream>>>(x1, ln2w, ln2b, n12);
  gemm256<2><<<(BTn / 256) * (HID / 256), 512, 0, stream>>>(n12, wT_fc, nullptr, hbuf, nullptr, BTn, HID, Cn, HID / 256);
  gemm256<1><<<(BTn / 256) * (Cn / 256), 512, 0, stream>>>(hbuf, wT_mp, x1, nullptr, out, BTn, Cn, HID, Cn / 256);
}

// Round 2
// 883.400 us; speedup vs baseline: 1.0410x; 1.0283x over previous
//
#include <hip/hip_runtime.h>
#include <stdint.h>
#include <math.h>

// Problem constants (B=2, T=2048, C=2048, NH=16, NG=4, HS=128)
#define Tn   2048
#define Cn   2048
#define BTn  4096          // B*T
#define NQKV 3072          // (16+2*4)*128
#define HID  8192

typedef unsigned short u16;
typedef float f32x4 __attribute__((ext_vector_type(4)));
typedef short s16x8 __attribute__((ext_vector_type(8)));   // 8 bf16 in 4 VGPRs

__device__ __forceinline__ float b2f(u16 u) { return __uint_as_float(((unsigned)u) << 16); }
__device__ __forceinline__ u16 f2b(float f) {
  unsigned i = __float_as_uint(f);
  return (u16)((i + 0x7fffu + ((i >> 16) & 1u)) >> 16);   // RNE
}

// async 16B global->LDS (lds dest is wave-uniform base; HW scatters lane*16)
__device__ __forceinline__ void g2l16(const void* g, void* l) {
  __builtin_amdgcn_global_load_lds((const __attribute__((address_space(1))) unsigned int*)g,
                                   (__attribute__((address_space(3))) unsigned int*)l,
                                   16, 0, 0);
}

// ------- tiled transpose + fp32->bf16 cast: out[c][r] = bf16(in[r][c]) -------
__global__ __launch_bounds__(256) void transpose_f2b(const float* __restrict__ in,
                                                     u16* __restrict__ out, int R, int C) {
  __shared__ float tile[32][33];
  int bx = blockIdx.x * 32, by = blockIdx.y * 32;
  int tx = threadIdx.x, ty = threadIdx.y;  // (32,8)
  #pragma unroll
  for (int j = 0; j < 32; j += 8)
    tile[ty + j][tx] = in[(size_t)(by + ty + j) * C + bx + tx];
  __syncthreads();
  #pragma unroll
  for (int j = 0; j < 32; j += 8)
    out[(size_t)(bx + ty + j) * R + by + tx] = f2b(tile[tx][ty + j]);
}

// ------- tiled u16 transpose with batch dim: out[z][c][r] = in[z][r][c] -------
__global__ __launch_bounds__(256) void transpose_u16(const u16* __restrict__ in,
                                                     u16* __restrict__ out, int R, int C) {
  __shared__ u16 tile[32][33];
  const size_t zb = (size_t)blockIdx.z * R * C;
  int bx = blockIdx.x * 32, by = blockIdx.y * 32;
  int tx = threadIdx.x, ty = threadIdx.y;  // (32,8)
  #pragma unroll
  for (int j = 0; j < 32; j += 8)
    tile[ty + j][tx] = in[zb + (size_t)(by + ty + j) * C + bx + tx];
  __syncthreads();
  #pragma unroll
  for (int j = 0; j < 32; j += 8)
    out[zb + (size_t)(bx + ty + j) * R + by + tx] = tile[tx][ty + j];
}

// ---------------- fp32 vector copy (residual prefill for split-K) ----------------
__global__ __launch_bounds__(256)
void copy_f32(const float* __restrict__ in, float* __restrict__ out) {
  const long i = ((long)blockIdx.x * 256 + threadIdx.x) * 4;
  *(f32x4*)(out + i) = *(const f32x4*)(in + i);
}

// ---------------- layernorm: fp32 in, bf16 out ----------------
__global__ __launch_bounds__(256)
void layernorm_k(const float* __restrict__ x, const float* __restrict__ w,
                 const float* __restrict__ bb, u16* __restrict__ out) {
  __shared__ float red[256];
  __shared__ float sm, sv;
  const int tid = threadIdx.x;
  const long row = blockIdx.x;
  const float* xr = x + row * (long)Cn;
  float v[8];
  float s = 0.f;
  #pragma unroll
  for (int i = 0; i < 8; ++i) { v[i] = xr[i * 256 + tid]; s += v[i]; }
  red[tid] = s; __syncthreads();
  for (int st = 128; st > 0; st >>= 1) { if (tid < st) red[tid] += red[tid + st]; __syncthreads(); }
  if (tid == 0) sm = red[0] * (1.f / Cn);
  __syncthreads();
  const float mean = sm;
  float s2 = 0.f;
  #pragma unroll
  for (int i = 0; i < 8; ++i) { float d = v[i] - mean; s2 += d * d; }
  red[tid] = s2; __syncthreads();
  for (int st = 128; st > 0; st >>= 1) { if (tid < st) red[tid] += red[tid + st]; __syncthreads(); }
  if (tid == 0) sv = rsqrtf(red[0] * (1.f / Cn) + 1e-5f);
  __syncthreads();
  const float rstd = sv;
  #pragma unroll
  for (int i = 0; i < 8; ++i) {
    int c = i * 256 + tid;
    out[row * (long)Cn + c] = f2b((v[i] - mean) * rstd * w[c] + bb[c]);
  }
}

// ---- RoPE + split qkv(bf16) -> q[b,h,t,d], k[b,g,t,d], v[b,g,t,d] (bf16) ----
__global__ __launch_bounds__(256)
void rope_split(const u16* __restrict__ qkv, const float* __restrict__ cs,
                const float* __restrict__ sn, u16* __restrict__ q,
                u16* __restrict__ k, u16* __restrict__ v) {
  const long idx = (long)blockIdx.x * 256 + threadIdx.x;
  const int row = (int)(idx / NQKV);       // b*T + t
  const int col = (int)(idx % NQKV);
  const int b = row >> 11, t = row & 2047;
  const int g = col / 768, rr = col % 768, s = rr >> 7, d = rr & 127;
  const u16 raw = qkv[idx];
  if (s == 5) { v[((long)(b * 4 + g) * Tn + t) * 128 + d] = raw; return; }
  const float xv = b2f(raw);
  const float x2 = b2f(qkv[idx - d + (d ^ 64)]);
  const float c = cs[t * 128 + d];
  const float si = sn[t * 128 + d];
  const float rot = (d < 64) ? -x2 : x2;
  const float o = xv * c + rot * si;
  if (s == 4) k[((long)(b * 4 + g) * Tn + t) * 128 + d] = f2b(o);
  else        q[((long)(b * 16 + g * 4 + s) * Tn + t) * 128 + d] = f2b(o);
}

// ------------- MFMA flash attention (causal GQA), bf16 I/O -------------
// Grid (T/64, B*NH). 4 waves; wave w owns Q rows bx*64+w*16 .. +15.
__global__ __launch_bounds__(256, 2)
void attn_flash(const u16* __restrict__ q, const u16* __restrict__ k,
                const u16* __restrict__ vt, u16* __restrict__ y) {
  __shared__ __align__(16) u16 Ks[4 * 64 * 32];     // 16 KB
  __shared__ __align__(16) u16 Vs[2 * 128 * 32];    // 16 KB
  __shared__ __align__(16) u16 Ps[4][2 * 16 * 32];  // 8 KB (per-wave)
  const int tid = threadIdx.x, wave = tid >> 6, lane = tid & 63;
  const int fr = lane & 15, quad = lane >> 4;
  const int lr4 = lane >> 2, lc8 = (lane & 3) << 3;
  const int bx = blockIdx.x, bh = blockIdx.y;
  const int b = bh >> 4, h = bh & 15, g = h >> 2;
  const int bg = b * 4 + g;
  const u16* kg = k + (size_t)bg * Tn * 128;
  const u16* vg = vt + (size_t)bg * 128 * Tn;
  const int q0 = bx * 64 + wave * 16;

  // Q fragments in registers: A[m=fr][k=kc*32+quad*8+j]
  s16x8 qf[4];
  {
    const u16* qrow = q + ((size_t)bh * Tn + q0 + fr) * 128;
    #pragma unroll
    for (int kc = 0; kc < 4; ++kc)
      qf[kc] = *(const s16x8*)(qrow + kc * 32 + quad * 8);
  }
  f32x4 o_acc[8] = {};                 // O[16][128], C-layout per 16-col tile
  float m_r[4], l_r[4];
  #pragma unroll
  for (int r = 0; r < 4; ++r) { m_r[r] = -1e30f; l_r[r] = 0.f; }
  const float scale = 0.08838834764831845f;  // 1/sqrt(128)

  for (int step = 0; step <= bx; ++step) {
    const int j0 = step * 64;
    __syncthreads();                   // prior iter's LDS reads done
    #pragma unroll
    for (int kc = 0; kc < 4; ++kc)
      g2l16(kg + (size_t)(j0 + wave * 16 + lr4) * 128 + kc * 32 + lc8,
            Ks + kc * 2048 + wave * 16 * 32);
    #pragma unroll
    for (int kc = 0; kc < 2; ++kc)
      #pragma unroll
      for (int hh = 0; hh < 2; ++hh)
        g2l16(vg + (size_t)(wave * 32 + hh * 16 + lr4) * Tn + j0 + kc * 32 + lc8,
              Vs + kc * 4096 + (wave * 32 + hh * 16) * 32);
    __syncthreads();                   // vmcnt(0) drain by compiler

    // S = Q * K^T  (16x64 per wave)
    f32x4 s[4] = {};
    #pragma unroll
    for (int kc = 0; kc < 4; ++kc)
      #pragma unroll
      for (int nt = 0; nt < 4; ++nt) {
        s16x8 bf = *(const s16x8*)(Ks + kc * 2048 + (nt * 16 + fr) * 32 + quad * 8);
        s[nt] = __builtin_amdgcn_mfma_f32_16x16x32_bf16(qf[kc], bf, s[nt], 0, 0, 0);
      }

    // online softmax; rows = q0 + quad*4 + r, cols = j0 + nt*16 + fr
    const bool diag = (step == bx);
    #pragma unroll
    for (int r = 0; r < 4; ++r) {
      float vmax = -1e30f;
      #pragma unroll
      for (int nt = 0; nt < 4; ++nt) {
        float sv = s[nt][r] * scale;
        if (diag && (j0 + nt * 16 + fr) > (q0 + quad * 4 + r)) sv = -1e30f;
        s[nt][r] = sv;
        vmax = fmaxf(vmax, sv);
      }
      #pragma unroll
      for (int mk = 1; mk < 16; mk <<= 1) vmax = fmaxf(vmax, __shfl_xor(vmax, mk, 64));
      const float mnew = fmaxf(m_r[r], vmax);
      const float alpha = __expf(m_r[r] - mnew);
      float rsum = 0.f;
      #pragma unroll
      for (int nt = 0; nt < 4; ++nt) {
        float pv = __expf(s[nt][r] - mnew);
        s[nt][r] = pv; rsum += pv;
      }
      #pragma unroll
      for (int mk = 1; mk < 16; mk <<= 1) rsum += __shfl_xor(rsum, mk, 64);
      l_r[r] = l_r[r] * alpha + rsum;
      m_r[r] = mnew;
      #pragma unroll
      for (int nt = 0; nt < 8; ++nt) o_acc[nt][r] *= alpha;
    }

    // P (C-layout) -> LDS panels (bf16), then A-frag reads
    u16* pw = Ps[wave];
    #pragma unroll
    for (int nt = 0; nt < 4; ++nt) {
      const int col = nt * 16 + fr, pan = col >> 5, cc = col & 31;
      #pragma unroll
      for (int r = 0; r < 4; ++r)
        pw[pan * 512 + (quad * 4 + r) * 32 + cc] = f2b(s[nt][r]);
    }
    // O += P * V  (k = t-dim, 2 panels of 32)
    #pragma unroll
    for (int kc = 0; kc < 2; ++kc) {
      s16x8 af = *(const s16x8*)(pw + kc * 512 + fr * 32 + quad * 8);
      #pragma unroll
      for (int nt = 0; nt < 8; ++nt) {
        s16x8 bf = *(const s16x8*)(Vs + kc * 4096 + (nt * 16 + fr) * 32 + quad * 8);
        o_acc[nt] = __builtin_amdgcn_mfma_f32_16x16x32_bf16(af, bf, o_acc[nt], 0, 0, 0);
      }
    }
  }

  // epilogue: y[b, t, h*128 + d] = O / l
  #pragma unroll
  for (int r = 0; r < 4; ++r) {
    const float inv = 1.f / l_r[r];
    const size_t row = (size_t)(b * Tn + q0 + quad * 4 + r) * Cn + h * 128;
    #pragma unroll
    for (int nt = 0; nt < 8; ++nt)
      y[row + nt * 16 + fr] = f2b(o_acc[nt][r] * inv);
  }
}

// ================= 256x256 8-phase MFMA GEMM (T2+T3+T4+T5) =================
// BM=BN=256, BK=64, 512 threads = 8 waves (2M x 4N), per-wave C = 128x64.
// LDS 128 KB: A[2buf][2half][128x64 bf16], B same at +64KB.
// ONE trailing barrier per phase (no leading barrier): WAR safety = each
// wave's lgkmcnt-drain precedes its barrier arrival; RAW safety = per-wave
// counted vmcnt at P4/P8 + that barrier. Waves skew inside a phase ->
// cross-wave ds_read || MFMA overlap (this round's change).
// Phase: {ds_read frags | stage 1 half-tile} -> lgkmcnt -> setprio(1)
// 16xMFMA setprio(0) -> [vmcnt(4) @P4/P8] -> barrier.
// Split-K via gridDim.y (EPI 3: fp32 atomicAdd into prefilled residual).
// EPI 0: ob=bf16(acc); EPI 1: of=acc+res; EPI 2: ob=bf16(gelu(acc)); EPI 3: atomic
#define BAR  __builtin_amdgcn_s_barrier()
#define LG0  asm volatile("s_waitcnt lgkmcnt(0)" ::: "memory")
#define RD_A(BUF, MI4)                                                                  \
  { _Pragma("unroll") for (int m_ = 0; m_ < 4; ++m_) {                                  \
      _Pragma("unroll") for (int k_ = 0; k_ < 2; ++k_)                                  \
        ar[m_][k_] = *(const s16x8*)(Sb + (BUF) * 32768 + aBase +                       \
                                     (((MI4) + m_) << 11) + (k_ << 10) + fragoff); } }
#define RD_B(BUF, NI2, DST)                                                             \
  { _Pragma("unroll") for (int n_ = 0; n_ < 2; ++n_) {                                  \
      _Pragma("unroll") for (int k_ = 0; k_ < 2; ++k_)                                  \
        DST[n_][k_] = *(const s16x8*)(Sb + (BUF) * 32768 + bBase +                      \
                                      (((NI2) + n_) << 11) + (k_ << 10) + fragoff); } }
#define MM(MB, NB, BR)                                                                  \
  { __builtin_amdgcn_s_setprio(1);                                                     \
    _Pragma("unroll") for (int m_ = 0; m_ < 4; ++m_) {                                  \
      _Pragma("unroll") for (int n_ = 0; n_ < 2; ++n_) {                                \
        _Pragma("unroll") for (int k_ = 0; k_ < 2; ++k_)                                \
          acc[(MB) + m_][(NB) + n_] = __builtin_amdgcn_mfma_f32_16x16x32_bf16(          \
              ar[m_][k_], BR[n_][k_], acc[(MB) + m_][(NB) + n_], 0, 0, 0); } }          \
    __builtin_amdgcn_s_setprio(0); }

template <int EPI>
__global__ __launch_bounds__(512, 2)
void gemm256(const u16* __restrict__ A, const u16* __restrict__ Bt,
             const float* __restrict__ res, u16* __restrict__ ob,
             float* __restrict__ of, int N, int Kl, int ld, int num_n) {
  __shared__ __align__(16) u16 S[65536];   // 128 KB
  char* Sb = (char*)S;

  // split-K: this block covers k-range [blockIdx.y*Kl, +Kl)
  const long koff = (long)blockIdx.y * Kl;
  A += koff; Bt += koff;

  // XCD-aware 2x2-patch swizzle (pid.x only; grid.x % 8 == 0 for all shapes)
  const int pid = blockIdx.x;
  const int xcd = pid & 7, idx = pid >> 3;
  const int jj = idx & 3;
  const int gp = (idx >> 2) * 8 + xcd;
  const int npc = num_n >> 1;
  const int pr = gp / npc, pc = gp - pr * npc;
  const long m0 = (long)(pr * 2 + (jj >> 1)) * 256;
  const long n0 = (long)(pc * 2 + (jj & 1)) * 256;

  const int tid = (int)threadIdx.x;
  const int wave = tid >> 6, lane = tid & 63;
  const int wr = wave >> 2, wc = wave & 3;          // wave grid 2M x 4N
  const int fr = lane & 15, quad = lane >> 4;
  // fragment ds_read byte offset within 16KB region, st_16x32-swizzled
  const int fragoff = (fr * 64 + quad * 16) ^ (((fr >> 3) & 1) << 5);
  const int aBase = wr * 16384;                          // A half = wr
  const int bBase = 65536 + (wc >> 1) * 16384 + ((wc & 1) << 13);  // B half/quarter

  // staging: linear LDS dest d -> logical l = d ^ swz -> (row, kbyte) source
  int srow[2], skcb[2];
  #pragma unroll
  for (int rr = 0; rr < 2; ++rr) {
    const int d = rr * 8192 + wave * 1024 + lane * 16;
    const int l = d ^ (((d >> 9) & 1) << 5);
    srow[rr] = ((l >> 11) << 4) | ((l >> 6) & 15);
    skcb[rr] = (((l >> 10) & 1) << 6) | (l & 63);
  }
  auto stage = [&](const u16* __restrict__ src, long grow0, int kt, int regionByte) {
    #pragma unroll
    for (int rr = 0; rr < 2; ++rr)
      g2l16((const char*)src + (grow0 + srow[rr]) * (long)ld * 2 + (long)kt * 128 + skcb[rr],
            Sb + regionByte + rr * 8192 + wave * 1024);
  };

  const int nk = Kl >> 6;    // 64-wide K-tiles (even, >=8 for all shapes here)
  const int nk2 = nk >> 1;

  // prologue: tile0 -> buf0 (A h0,h1 + B h0,h1), tile1 B -> buf1
  stage(A,  m0,       0, 0);
  stage(A,  m0 + 128, 0, 16384);
  stage(Bt, n0,       0, 65536);
  stage(Bt, n0 + 128, 0, 81920);
  stage(Bt, n0,       1, 98304);
  stage(Bt, n0 + 128, 1, 114688);
  asm volatile("s_waitcnt vmcnt(4)" ::: "memory");   // tile0 landed
  BAR;

  s16x8 ar[4][2], br0[2][2], br1[2][2];
  f32x4 acc[8][4] = {};

  for (int i = 0; i < nk2; ++i) {
    const int t1 = 2 * i + 1, s0 = 2 * i + 2, s1 = 2 * i + 3;
    const bool v0 = (s0 < nk), v1 = (s1 < nk);
    // ---------- K-tile 2i from buf0: phases P1-P4 ----------
    // P1: A mi0-3 + B ni0-1 (12 reads); stage buf1.A h0 <- tile t1
    RD_A(0, 0); RD_B(0, 0, br0);
    stage(A, m0, t1, 32768);
    LG0; MM(0, 0, br0); BAR;
    // P2: B ni2-3; stage buf1.A h1
    RD_B(0, 2, br1);
    stage(A, m0 + 128, t1, 49152);
    LG0; MM(0, 2, br1); BAR;
    // P3: A mi4-7; stage buf0.B h0 <- tile s0 (buf0.B reads drained @P2)
    RD_A(0, 4);
    if (v0) stage(Bt, n0, s0, 65536);
    LG0; MM(4, 2, br1); BAR;
    // P4: no reads; stage buf0.B h1; counted vmcnt -> buf1 (t1) fully landed
    if (v0) stage(Bt, n0 + 128, s0, 81920);
    MM(4, 0, br0);
    if (v0) { asm volatile("s_waitcnt vmcnt(4)" ::: "memory"); }
    else    { asm volatile("s_waitcnt vmcnt(0)" ::: "memory"); }
    BAR;
    // ---------- K-tile 2i+1 from buf1: phases P5-P8 ----------
    // P5: stage buf0.A h0 <- tile s0 (buf0.A reads drained @P3)
    RD_A(1, 0); RD_B(1, 0, br0);
    if (v0) stage(A, m0, s0, 0);
    LG0; MM(0, 0, br0); BAR;
    // P6: stage buf0.A h1
    RD_B(1, 2, br1);
    if (v0) stage(A, m0 + 128, s0, 16384);
    LG0; MM(0, 2, br1); BAR;
    // P7: stage buf1.B h0 <- tile s1 (buf1.B reads drained @P6)
    RD_A(1, 4);
    if (v1) stage(Bt, n0, s1, 98304);
    LG0; MM(4, 2, br1); BAR;
    // P8: stage buf1.B h1; counted vmcnt -> buf0 (s0) fully landed
    if (v1) stage(Bt, n0 + 128, s1, 114688);
    MM(4, 0, br0);
    asm volatile("s_waitcnt vmcnt(4)" ::: "memory");
    BAR;
  }

  // epilogue: C[row][col], row = m0+wr*128+mi*16+quad*4+r, col = n0+wc*64+ni*16+fr
  #pragma unroll
  for (int mi = 0; mi < 8; ++mi)
    #pragma unroll
    for (int ni = 0; ni < 4; ++ni)
      #pragma unroll
      for (int r = 0; r < 4; ++r) {
        const long row = m0 + wr * 128 + mi * 16 + quad * 4 + r;
        const long col = n0 + wc * 64 + ni * 16 + fr;
        const long idx2 = row * N + col;
        const float vv = acc[mi][ni][r];
        if (EPI == 0) ob[idx2] = f2b(vv);
        else if (EPI == 1) of[idx2] = vv + res[idx2];
        else if (EPI == 2) ob[idx2] = f2b(0.5f * vv * (1.0f + erff(vv * 0.70710678118654752f)));
        else atomicAdd(&of[idx2], vv);
      }
}

extern "C" void kernel_launch(void* const* d_in, const int* in_sizes, int n_in,
                              void* d_out, int out_size, void* d_ws, size_t ws_size,
                              hipStream_t stream) {
  (void)in_sizes; (void)n_in; (void)out_size; (void)ws_size;
  const float* x      = (const float*)d_in[0];
  const float* cosb   = (const float*)d_in[1];
  const float* sinb   = (const float*)d_in[2];
  const float* ln1w   = (const float*)d_in[3];
  const float* ln1b   = (const float*)d_in[4];
  const float* ln2w   = (const float*)d_in[5];
  const float* ln2b   = (const float*)d_in[6];
  const float* w_attn = (const float*)d_in[7];
  const float* w_proj = (const float*)d_in[8];
  const float* w_fc   = (const float*)d_in[9];
  const float* w_mp   = (const float*)d_in[10];
  float* out = (float*)d_out;

  char* p = (char*)d_ws;
  auto alloc = [&](size_t bytes) { char* r = p; p += (bytes + 255) & ~(size_t)255; return (void*)r; };
  u16*  wT_attn = (u16*)alloc((size_t)NQKV * Cn * 2);   // bf16 [3072][2048]
  u16*  wT_proj = (u16*)alloc((size_t)Cn * Cn * 2);     // bf16 [2048][2048]
  u16*  wT_fc   = (u16*)alloc((size_t)HID * Cn * 2);    // bf16 [8192][2048]
  u16*  wT_mp   = (u16*)alloc((size_t)Cn * HID * 2);    // bf16 [2048][8192]
  u16*  n12     = (u16*)alloc((size_t)BTn * Cn * 2);    // n1 / vt(attn phase) / n2
  u16*  qkv     = (u16*)alloc((size_t)BTn * NQKV * 2);  // qkv, then y (bf16)
  u16*  qb      = (u16*)alloc((size_t)2 * 16 * Tn * 128 * 2);
  u16*  kb      = (u16*)alloc((size_t)2 * 4 * Tn * 128 * 2);
  u16*  vb      = (u16*)alloc((size_t)2 * 4 * Tn * 128 * 2);
  float* x1     = (float*)alloc((size_t)BTn * Cn * 4);  // residual stream (fp32)
  u16*  hbuf    = (u16*)alloc((size_t)BTn * HID * 2);   // gelu(fc) output (bf16)
  u16*  vt      = n12;                                  // [b,g,d,t] transposed V

  dim3 tb(32, 8);
  transpose_f2b<<<dim3(NQKV / 32, Cn / 32), tb, 0, stream>>>(w_attn, wT_attn, Cn, NQKV);
  transpose_f2b<<<dim3(Cn / 32, Cn / 32), tb, 0, stream>>>(w_proj, wT_proj, Cn, Cn);
  transpose_f2b<<<dim3(HID / 32, Cn / 32), tb, 0, stream>>>(w_fc, wT_fc, Cn, HID);
  transpose_f2b<<<dim3(Cn / 32, HID / 32), tb, 0, stream>>>(w_mp, wT_mp, HID, Cn);

  layernorm_k<<<BTn, 256, 0, stream>>>(x, ln1w, ln1b, n12);
  gemm256<0><<<(BTn / 256) * (NQKV / 256), 512, 0, stream>>>(n12, wT_attn, nullptr, qkv, nullptr, NQKV, Cn, Cn, NQKV / 256);
  rope_split<<<(int)(((long)BTn * NQKV) / 256), 256, 0, stream>>>(qkv, cosb, sinb, qb, kb, vb);
  transpose_u16<<<dim3(128 / 32, Tn / 32, 8), tb, 0, stream>>>(vb, vt, Tn, 128);
  attn_flash<<<dim3(Tn / 64, 32), 256, 0, stream>>>(qb, kb, vt, qkv /* y reuse */);
  // attn proj: split-K=2 (grid 128x2 = 256 blocks, full machine); x1 prefilled with x
  copy_f32<<<(int)(((long)BTn * Cn) / 1024), 256, 0, stream>>>(x, x1);
  gemm256<3><<<dim3((BTn / 256) * (Cn / 256), 2), 512, 0, stream>>>(qkv, wT_proj, nullptr, nullptr, x1, Cn, Cn / 2, Cn, Cn / 256);
  layernorm_k<<<BTn, 256, 0, stream>>>(x1, ln2w, ln2b, n12);
  gemm256<2><<<(BTn / 256) * (HID / 256), 512, 0, stream>>>(n12, wT_fc, nullptr, hbuf, nullptr, HID, Cn, Cn, HID / 256);
  // mlp proj: split-K=2; out prefilled with x1 (residual)
  copy_f32<<<(int)(((long)BTn * Cn) / 1024), 256, 0, stream>>>(x1, out);
  gemm256<3><<<dim3((BTn / 256) * (Cn / 256), 2), 512, 0, stream>>>(hbuf, wT_mp, nullptr, nullptr, out, Cn, HID / 2, HID, Cn / 256);
}